// Round 6
// baseline (202.270 us; speedup 1.0000x reference)
//
#include <hip/hip_runtime.h>
#include <math.h>

// Problem constants (B=4, H=16, S=4096, D=64, m=256)
#define DNORM   0.35355339059327376f   // sqrt(softmax_temp) = (1/8)^0.5
#define DIAG_F  0.0625f                // 0.5 * softmax_temp
#define HLM     2.772588722239781f     // log(256)/2
#define ROWS_TOTAL   262144            // B*H*S
#define FEAT_ELEMS   67108864          // B*H*S*256
#define ROWS_PER_BLK 128
#define NBLOCKS      2048              // ROWS_TOTAL / 128
#define BLKS_PER_BH  32                // 4096 / 128

using bf16x8 = __attribute__((ext_vector_type(8))) short;
using f32x4  = __attribute__((ext_vector_type(4))) float;

__device__ __forceinline__ unsigned short f2bf(float f) {
    unsigned int u = __builtin_bit_cast(unsigned int, f);
    u = (u + 0x7FFFu + ((u >> 16) & 1u)) >> 16;   // RNE
    return (unsigned short)u;
}

// ---------------------------------------------------------------------------
// Stage a 128x64 fp32 panel into MFMA fragment order (bf16), optionally
// scaling by DNORM (proj) and computing per-row diag (data). Fragment layout
// (per 16-row tile, per 32-elem half h): lane l <- row l&15, k = (l>>4)*8+e.
// Valid as either A or B operand (pack-symmetric). Reads fully coalesced.
// ---------------------------------------------------------------------------
template<bool SCALE, bool DIAG>
__device__ __forceinline__ void stage128(const float* __restrict__ src,
                                         unsigned short (*F)[2][64][8],
                                         float* diag_s, int t) {
    const float4* g = reinterpret_cast<const float4*>(src);
#pragma unroll
    for (int i = 0; i < 8; ++i) {
        int c = t & 15;            // chunk within row (4 floats)
        int m = t >> 4;            // row within 16-row tile
        float4 v = g[t + i * 256];
        if (SCALE) { v.x *= DNORM; v.y *= DNORM; v.z *= DNORM; v.w *= DNORM; }
        if (DIAG) {
            float ss = v.x * v.x + v.y * v.y + v.z * v.z + v.w * v.w;
            ss += __shfl_xor(ss, 1, 64);
            ss += __shfl_xor(ss, 2, 64);
            ss += __shfl_xor(ss, 4, 64);
            ss += __shfl_xor(ss, 8, 64);
            if (c == 0) diag_s[m + 16 * i] = ss * DIAG_F;
        }
        int h = c >> 3, dg = (c >> 1) & 3, half = c & 1;
        uint2 wv;
        wv.x = (unsigned int)f2bf(v.x) | ((unsigned int)f2bf(v.y) << 16);
        wv.y = (unsigned int)f2bf(v.z) | ((unsigned int)f2bf(v.w) << 16);
        *reinterpret_cast<uint2*>(&F[i][h][dg * 16 + m][half * 4]) = wv;
    }
}

// ---------------------------------------------------------------------------
// Swapped-operand MFMA core: acc[r][pt] = proj-tile(pt) x data-tile(w*2+r).
// D-layout (HW-verified): data row = lane&15, proj row (= feature sub-idx)
// = (lane>>4)*4 + reg. So each lane's 4 regs are 4 CONSECUTIVE features of
// one data row -> dwordx4 stores.
// ---------------------------------------------------------------------------
struct TileCtx { f32x4 acc[2][8]; int l, w; };

__device__ __forceinline__ void mfma_tiles(unsigned short (*Ds)[2][64][8],
                                           unsigned short (*Ps)[2][64][8],
                                           TileCtx& ctx) {
    int t = threadIdx.x;
    int l = t & 63, w = t >> 6;
    ctx.l = l; ctx.w = w;
    bf16x8 fd[2][2];
#pragma unroll
    for (int r = 0; r < 2; ++r)
#pragma unroll
        for (int h = 0; h < 2; ++h)
            fd[r][h] = *reinterpret_cast<bf16x8*>(&Ds[w * 2 + r][h][l][0]);
#pragma unroll
    for (int r = 0; r < 2; ++r)
#pragma unroll
        for (int pt = 0; pt < 8; ++pt)
            ctx.acc[r][pt] = f32x4{0.f, 0.f, 0.f, 0.f};
#pragma unroll
    for (int pt = 0; pt < 8; ++pt) {
        bf16x8 fp0 = *reinterpret_cast<bf16x8*>(&Ps[pt][0][l][0]);
        bf16x8 fp1 = *reinterpret_cast<bf16x8*>(&Ps[pt][1][l][0]);
#pragma unroll
        for (int r = 0; r < 2; ++r) {
            ctx.acc[r][pt] = __builtin_amdgcn_mfma_f32_16x16x32_bf16(fp0, fd[r][0], ctx.acc[r][pt], 0, 0, 0);
            ctx.acc[r][pt] = __builtin_amdgcn_mfma_f32_16x16x32_bf16(fp1, fd[r][1], ctx.acc[r][pt], 0, 0, 0);
        }
    }
}

// ---------------------------------------------------------------------------
// k max pass: per-block max of (|x| - diag) - HLM -> partials[bid] (d_ws)
// ---------------------------------------------------------------------------
__global__ __launch_bounds__(256) void kmax_kernel(
        const float* __restrict__ k, const float* __restrict__ proj,
        float* __restrict__ partials) {
    __shared__ unsigned short Ds[8][2][64][8];
    __shared__ unsigned short Ps[8][2][64][8];
    __shared__ float diag_s[ROWS_PER_BLK];
    __shared__ float red[4];
    int t = threadIdx.x;
    stage128<true,  false>(proj, Ps, nullptr, t);
    stage128<false, true >(k + (size_t)blockIdx.x * ROWS_PER_BLK * 64, Ds, diag_s, t);
    __syncthreads();
    TileCtx ctx;
    mfma_tiles(Ds, Ps, ctx);
    int l = ctx.l, w = ctx.w;
    float cand = -INFINITY;
#pragma unroll
    for (int r = 0; r < 2; ++r) {
        int row = (w * 2 + r) * 16 + (l & 15);
        float mx = 0.f;
#pragma unroll
        for (int pt = 0; pt < 8; ++pt) {
            f32x4 a = ctx.acc[r][pt];
            mx = fmaxf(mx, fmaxf(fmaxf(fabsf(a[0]), fabsf(a[1])),
                                 fmaxf(fabsf(a[2]), fabsf(a[3]))));
        }
        cand = fmaxf(cand, mx - diag_s[row]);
    }
#pragma unroll
    for (int s = 32; s; s >>= 1) cand = fmaxf(cand, __shfl_xor(cand, s, 64));
    if (l == 0) red[w] = cand;
    __syncthreads();
    if (t == 0)
        partials[blockIdx.x] =
            fmaxf(fmaxf(red[0], red[1]), fmaxf(red[2], red[3])) - HLM;
}

// ---------------------------------------------------------------------------
// Merged feature kernel: blocks [0,2048) = k features (k L3-hot from kmax),
// blocks [2048,4096) = q features. Wide dwordx4 NT stores.
// ---------------------------------------------------------------------------
__global__ __launch_bounds__(256) void feat_kernel(
        const float* __restrict__ q, const float* __restrict__ k,
        const float* __restrict__ proj, const float* __restrict__ partials,
        float* __restrict__ qf, float* __restrict__ qls,
        float* __restrict__ kf, float* __restrict__ kls) {
    __shared__ unsigned short Ds[8][2][64][8];
    __shared__ unsigned short Ps[8][2][64][8];
    __shared__ float diag_s[ROWS_PER_BLK];
    __shared__ float gls_s;
    int t = threadIdx.x;
    bool is_q = blockIdx.x >= NBLOCKS;
    int bid = is_q ? (blockIdx.x - NBLOCKS) : blockIdx.x;
    const float* data = is_q ? q : k;
    float* feats = is_q ? qf : kf;

    stage128<true,  false>(proj, Ps, nullptr, t);
    stage128<false, true >(data + (size_t)bid * ROWS_PER_BLK * 64, Ds, diag_s, t);
    if (!is_q && t < 32) {
        float v = partials[(bid >> 5) * BLKS_PER_BH + t];
#pragma unroll
        for (int s = 16; s; s >>= 1) v = fmaxf(v, __shfl_xor(v, s, 64));
        if (t == 0) gls_s = v;
    }
    __syncthreads();
    TileCtx ctx;
    mfma_tiles(Ds, Ps, ctx);
    int l = ctx.l, w = ctx.w;
    float gls = 0.f;
    if (!is_q) {
        gls = gls_s;
        if ((bid & 31) == 0 && t == 0) kls[bid >> 5] = gls;
    }

#pragma unroll
    for (int r = 0; r < 2; ++r) {
        int row = (w * 2 + r) * 16 + (l & 15);
        float off;
        float mx = 0.f;
        if (is_q) {
            // per-row amax over all 256 features = max |x|; features of one
            // data row live in lanes {l, l^16, l^32} (same l&15)
#pragma unroll
            for (int pt = 0; pt < 8; ++pt) {
                f32x4 a = ctx.acc[r][pt];
                mx = fmaxf(mx, fmaxf(fmaxf(fabsf(a[0]), fabsf(a[1])),
                                     fmaxf(fabsf(a[2]), fabsf(a[3]))));
            }
            mx = fmaxf(mx, __shfl_xor(mx, 16, 64));
            mx = fmaxf(mx, __shfl_xor(mx, 32, 64));
            off = mx;
        } else {
            off = diag_s[row] + HLM + gls;
        }
        size_t R = (size_t)bid * ROWS_PER_BLK + row;
        float* o = feats + R * 256 + (l >> 4) * 4;
#pragma unroll
        for (int pt = 0; pt < 8; ++pt) {
            f32x4 a = ctx.acc[r][pt];
            f32x4 e1, e2;
            e1[0] = __expf(a[0] - off); e1[1] = __expf(a[1] - off);
            e1[2] = __expf(a[2] - off); e1[3] = __expf(a[3] - off);
            e2[0] = __expf(-a[0] - off); e2[1] = __expf(-a[1] - off);
            e2[2] = __expf(-a[2] - off); e2[3] = __expf(-a[3] - off);
            __builtin_nontemporal_store(e1, reinterpret_cast<f32x4*>(o + pt * 16));
            __builtin_nontemporal_store(e2, reinterpret_cast<f32x4*>(o + pt * 16 + 128));
        }
        if (is_q && l < 16) {
            // lane l holds the reduced mx for row (w*2+r)*16 + l
            qls[R] = mx - diag_s[row] - HLM;
        }
    }
}

extern "C" void kernel_launch(void* const* d_in, const int* in_sizes, int n_in,
                              void* d_out, int out_size, void* d_ws, size_t ws_size,
                              hipStream_t stream) {
    const float* q    = (const float*)d_in[0];
    const float* k    = (const float*)d_in[1];
    const float* proj = (const float*)d_in[2];

    float* out = (float*)d_out;
    float* qf  = out;                                       // (B,H,S,256)
    float* qls = out + (size_t)FEAT_ELEMS;                  // (B,H,S,1)
    float* kf  = out + (size_t)FEAT_ELEMS + ROWS_TOTAL;     // (B,H,S,256)
    float* kls = out + 2 * (size_t)FEAT_ELEMS + ROWS_TOTAL; // (B,H,1,1)

    float* partials = (float*)d_ws;                         // 2048 floats

    kmax_kernel<<<NBLOCKS, 256, 0, stream>>>(k, proj, partials);
    feat_kernel<<<2 * NBLOCKS, 256, 0, stream>>>(q, k, proj, partials,
                                                 qf, qls, kf, kls);
}

// Round 8
// 132.725 us; speedup vs baseline: 1.5240x; 1.5240x over previous
//
#include <hip/hip_runtime.h>
#include <math.h>

// Problem constants (B=4, H=16, S=4096, D=64, m=256)
#define DNORM   0.35355339059327376f   // sqrt(softmax_temp) = (1/8)^0.5
#define DIAG_F  0.0625f                // 0.5 * softmax_temp
#define HLM     2.772588722239781f     // log(256)/2
#define ROWS_TOTAL   262144            // B*H*S
#define FEAT_ELEMS   67108864          // B*H*S*256
#define ROWS_PER_BLK 128
#define NBLOCKS      2048              // ROWS_TOTAL / 128
#define BLKS_PER_BH  32                // 4096 / 128
#define OB_STRIDE    264               // fp32 words per buffered row (bank-spread)

// Wave-local LDS handoff fence: compiler memory barrier + wait for all LDS ops.
// Needed because the epilogue passes data cross-lane through LDS without a
// block barrier (per-thread alias analysis would otherwise reorder ds_read
// past ds_write).
#define LDS_FENCE() asm volatile("s_waitcnt lgkmcnt(0)" ::: "memory")

using bf16x8 = __attribute__((ext_vector_type(8))) short;
using f32x4  = __attribute__((ext_vector_type(4))) float;

__device__ __forceinline__ unsigned short f2bf(float f) {
    unsigned int u = __builtin_bit_cast(unsigned int, f);
    u = (u + 0x7FFFu + ((u >> 16) & 1u)) >> 16;   // RNE
    return (unsigned short)u;
}

// ---------------------------------------------------------------------------
// Stage a 128x64 fp32 panel into MFMA fragment order (bf16), optionally
// scaling by DNORM (proj) and computing per-row diag (data). Pack-symmetric
// (valid as A or B operand). Reads fully coalesced float4.
// ---------------------------------------------------------------------------
template<bool SCALE, bool DIAG>
__device__ __forceinline__ void stage128(const float* __restrict__ src,
                                         unsigned short (*F)[2][64][8],
                                         float* diag_s, int t) {
    const float4* g = reinterpret_cast<const float4*>(src);
#pragma unroll
    for (int i = 0; i < 8; ++i) {
        int c = t & 15;            // chunk within row (4 floats)
        int m = t >> 4;            // row within 16-row tile
        float4 v = g[t + i * 256];
        if (SCALE) { v.x *= DNORM; v.y *= DNORM; v.z *= DNORM; v.w *= DNORM; }
        if (DIAG) {
            float ss = v.x * v.x + v.y * v.y + v.z * v.z + v.w * v.w;
            ss += __shfl_xor(ss, 1, 64);
            ss += __shfl_xor(ss, 2, 64);
            ss += __shfl_xor(ss, 4, 64);
            ss += __shfl_xor(ss, 8, 64);
            if (c == 0) diag_s[m + 16 * i] = ss * DIAG_F;
        }
        int h = c >> 3, dg = (c >> 1) & 3, half = c & 1;
        uint2 wv;
        wv.x = (unsigned int)f2bf(v.x) | ((unsigned int)f2bf(v.y) << 16);
        wv.y = (unsigned int)f2bf(v.z) | ((unsigned int)f2bf(v.w) << 16);
        *reinterpret_cast<uint2*>(&F[i][h][dg * 16 + m][half * 4]) = wv;
    }
}

// ---------------------------------------------------------------------------
// Swapped-operand MFMA core: acc[r][pt] = proj-tile(pt) x data-tile(w*2+r).
// D-layout: data row = lane&15, feature sub-idx = (lane>>4)*4 + reg.
// ---------------------------------------------------------------------------
struct TileCtx { f32x4 acc[2][8]; int l, w; };

__device__ __forceinline__ void mfma_tiles(unsigned short (*Ds)[2][64][8],
                                           unsigned short (*Ps)[2][64][8],
                                           TileCtx& ctx) {
    int t = threadIdx.x;
    int l = t & 63, w = t >> 6;
    ctx.l = l; ctx.w = w;
    bf16x8 fd[2][2];
#pragma unroll
    for (int r = 0; r < 2; ++r)
#pragma unroll
        for (int h = 0; h < 2; ++h)
            fd[r][h] = *reinterpret_cast<bf16x8*>(&Ds[w * 2 + r][h][l][0]);
#pragma unroll
    for (int r = 0; r < 2; ++r)
#pragma unroll
        for (int pt = 0; pt < 8; ++pt)
            ctx.acc[r][pt] = f32x4{0.f, 0.f, 0.f, 0.f};
#pragma unroll
    for (int pt = 0; pt < 8; ++pt) {
        bf16x8 fp0 = *reinterpret_cast<bf16x8*>(&Ps[pt][0][l][0]);
        bf16x8 fp1 = *reinterpret_cast<bf16x8*>(&Ps[pt][1][l][0]);
#pragma unroll
        for (int r = 0; r < 2; ++r) {
            ctx.acc[r][pt] = __builtin_amdgcn_mfma_f32_16x16x32_bf16(fp0, fd[r][0], ctx.acc[r][pt], 0, 0, 0);
            ctx.acc[r][pt] = __builtin_amdgcn_mfma_f32_16x16x32_bf16(fp1, fd[r][1], ctx.acc[r][pt], 0, 0, 0);
        }
    }
}

// ---------------------------------------------------------------------------
// k max pass: per-block max of (|x| - diag) - HLM -> partials[bid] (d_ws)
// ---------------------------------------------------------------------------
__global__ __launch_bounds__(256) void kmax_kernel(
        const float* __restrict__ k, const float* __restrict__ proj,
        float* __restrict__ partials) {
    __shared__ unsigned short Ds[8][2][64][8];
    __shared__ unsigned short Ps[8][2][64][8];
    __shared__ float diag_s[ROWS_PER_BLK];
    __shared__ float red[4];
    int t = threadIdx.x;
    stage128<true,  false>(proj, Ps, nullptr, t);
    stage128<false, true >(k + (size_t)blockIdx.x * ROWS_PER_BLK * 64, Ds, diag_s, t);
    __syncthreads();
    TileCtx ctx;
    mfma_tiles(Ds, Ps, ctx);
    int l = ctx.l, w = ctx.w;
    float cand = -INFINITY;
#pragma unroll
    for (int r = 0; r < 2; ++r) {
        int row = (w * 2 + r) * 16 + (l & 15);
        float mx = 0.f;
#pragma unroll
        for (int pt = 0; pt < 8; ++pt) {
            f32x4 a = ctx.acc[r][pt];
            mx = fmaxf(mx, fmaxf(fmaxf(fabsf(a[0]), fabsf(a[1])),
                                 fmaxf(fabsf(a[2]), fabsf(a[3]))));
        }
        cand = fmaxf(cand, mx - diag_s[row]);
    }
#pragma unroll
    for (int s = 32; s; s >>= 1) cand = fmaxf(cand, __shfl_xor(cand, s, 64));
    if (l == 0) red[w] = cand;
    __syncthreads();
    if (t == 0)
        partials[blockIdx.x] =
            fmaxf(fmaxf(red[0], red[1]), fmaxf(red[2], red[3])) - HLM;
}

// ---------------------------------------------------------------------------
// Merged feature kernel with full-line streaming epilogue:
// blocks [0,2048) = k features, [2048,4096) = q features.
// Epilogue bounces acc through a per-wave LDS slice so every global store
// instruction writes ONE complete 1 KB output row (64 lanes x 16 B
// contiguous) -> no partial-cache-line HBM traffic. Wave-local fences order
// the fill/drain handoff.
// ---------------------------------------------------------------------------
__global__ __launch_bounds__(256) void feat_kernel(
        const float* __restrict__ q, const float* __restrict__ k,
        const float* __restrict__ proj, const float* __restrict__ partials,
        float* __restrict__ qf, float* __restrict__ qls,
        float* __restrict__ kf, float* __restrict__ kls) {
    // staging (32 KB) and out-bounce (33 KB) time-share one buffer
    __shared__ __align__(16) unsigned char smem[4 * 8 * OB_STRIDE * 4];
    __shared__ float diag_s[ROWS_PER_BLK];
    __shared__ float gls_s;
    auto Ds = reinterpret_cast<unsigned short(*)[2][64][8]>(smem);
    auto Ps = reinterpret_cast<unsigned short(*)[2][64][8]>(smem + 16384);
    float* outb = reinterpret_cast<float*>(smem);

    int t = threadIdx.x;
    bool is_q = blockIdx.x >= NBLOCKS;
    int bid = is_q ? (blockIdx.x - NBLOCKS) : blockIdx.x;
    const float* data = is_q ? q : k;
    float* feats = is_q ? qf : kf;

    stage128<true,  false>(proj, Ps, nullptr, t);
    stage128<false, true >(data + (size_t)bid * ROWS_PER_BLK * 64, Ds, diag_s, t);
    if (!is_q && t < 32) {
        float v = partials[(bid >> 5) * BLKS_PER_BH + t];
#pragma unroll
        for (int s = 16; s; s >>= 1) v = fmaxf(v, __shfl_xor(v, s, 64));
        if (t == 0) gls_s = v;
    }
    __syncthreads();
    TileCtx ctx;
    mfma_tiles(Ds, Ps, ctx);
    int l = ctx.l, w = ctx.w;
    float gls = 0.f;
    if (!is_q) {
        gls = gls_s;
        if ((bid & 31) == 0 && t == 0) kls[bid >> 5] = gls;
    }
    __syncthreads();   // all waves done reading Ps/Ds before outb reuse

    float* ob = outb + w * (8 * OB_STRIDE);
    int myrow = l & 15;         // row within this wave's 16-row tile
    int g = l >> 4;             // 4-feature sub-chunk index

#pragma unroll
    for (int r = 0; r < 2; ++r) {
        int row = (w * 2 + r) * 16 + myrow;
        float off;
        if (is_q) {
            float mx = 0.f;     // max over concat[x,-x] = max |x|
#pragma unroll
            for (int pt = 0; pt < 8; ++pt) {
                f32x4 a = ctx.acc[r][pt];
                mx = fmaxf(mx, fmaxf(fmaxf(fabsf(a[0]), fabsf(a[1])),
                                     fmaxf(fabsf(a[2]), fabsf(a[3]))));
            }
            mx = fmaxf(mx, __shfl_xor(mx, 16, 64));
            mx = fmaxf(mx, __shfl_xor(mx, 32, 64));
            off = mx;
        } else {
            off = diag_s[row] + HLM + gls;
        }

#pragma unroll
        for (int p = 0; p < 2; ++p) {
            if ((myrow >> 3) == p) {
                float* obr = ob + (myrow & 7) * OB_STRIDE + g * 4;
#pragma unroll
                for (int pt = 0; pt < 8; ++pt) {
                    f32x4 a = ctx.acc[r][pt];
                    f32x4 e1, e2;
                    e1[0] = __expf(a[0] - off); e1[1] = __expf(a[1] - off);
                    e1[2] = __expf(a[2] - off); e1[3] = __expf(a[3] - off);
                    e2[0] = __expf(-a[0] - off); e2[1] = __expf(-a[1] - off);
                    e2[2] = __expf(-a[2] - off); e2[3] = __expf(-a[3] - off);
                    *reinterpret_cast<f32x4*>(obr + pt * 16)       = e1;
                    *reinterpret_cast<f32x4*>(obr + pt * 16 + 128) = e2;
                }
            }
            LDS_FENCE();   // fill (cross-lane) visible before drain reads
            // drain 8 complete rows: one 1 KB-contiguous store per instruction
            size_t Rb = (size_t)bid * ROWS_PER_BLK + (w * 2 + r) * 16 + p * 8;
#pragma unroll
            for (int j = 0; j < 8; ++j) {
                f32x4 v = *reinterpret_cast<f32x4*>(ob + j * OB_STRIDE + l * 4);
                __builtin_nontemporal_store(
                    v, reinterpret_cast<f32x4*>(feats + (Rb + j) * 256 + l * 4));
            }
            LDS_FENCE();   // drain reads done before next fill overwrites (WAR)
        }
        if (is_q && l < 16) {
            size_t R = (size_t)bid * ROWS_PER_BLK + row;
            qls[R] = off - diag_s[row] - HLM;
        }
    }
}

extern "C" void kernel_launch(void* const* d_in, const int* in_sizes, int n_in,
                              void* d_out, int out_size, void* d_ws, size_t ws_size,
                              hipStream_t stream) {
    const float* q    = (const float*)d_in[0];
    const float* k    = (const float*)d_in[1];
    const float* proj = (const float*)d_in[2];

    float* out = (float*)d_out;
    float* qf  = out;                                       // (B,H,S,256)
    float* qls = out + (size_t)FEAT_ELEMS;                  // (B,H,S,1)
    float* kf  = out + (size_t)FEAT_ELEMS + ROWS_TOTAL;     // (B,H,S,256)
    float* kls = out + 2 * (size_t)FEAT_ELEMS + ROWS_TOTAL; // (B,H,1,1)

    float* partials = (float*)d_ws;                         // 2048 floats

    kmax_kernel<<<NBLOCKS, 256, 0, stream>>>(k, proj, partials);
    feat_kernel<<<2 * NBLOCKS, 256, 0, stream>>>(q, k, proj, partials,
                                                 qf, qls, kf, kls);
}

// Round 9
// 119.870 us; speedup vs baseline: 1.6874x; 1.1072x over previous
//
#include <hip/hip_runtime.h>
#include <math.h>

// Problem constants (B=4, H=16, S=4096, D=64, m=256)
#define DNORM   0.35355339059327376f   // sqrt(softmax_temp) = (1/8)^0.5
#define DIAG_F  0.0625f                // 0.5 * softmax_temp
#define HLM     2.772588722239781f     // log(256)/2
#define ROWS_TOTAL   262144            // B*H*S
#define FEAT_ELEMS   67108864          // B*H*S*256
#define ROWS_PER_BLK 128
#define NBLOCKS      2048              // ROWS_TOTAL / 128
#define BLKS_PER_BH  32                // 4096 / 128
#define OB_STRIDE    264               // fp32 words per buffered row (bank-spread)

// Wave-local LDS handoff fence (cross-lane pass through LDS without a block
// barrier): memory clobber stops compiler reordering, lgkmcnt(0) orders HW.
#define LDS_FENCE() asm volatile("s_waitcnt lgkmcnt(0)" ::: "memory")

using bf16x8 = __attribute__((ext_vector_type(8))) short;
using f32x4  = __attribute__((ext_vector_type(4))) float;

__device__ __forceinline__ unsigned short f2bf(float f) {
    unsigned int u = __builtin_bit_cast(unsigned int, f);
    u = (u + 0x7FFFu + ((u >> 16) & 1u)) >> 16;   // RNE
    return (unsigned short)u;
}

__device__ __forceinline__ bf16x8 pack8(float4 a, float4 b) {
    bf16x8 r;
    r[0] = (short)f2bf(a.x); r[1] = (short)f2bf(a.y);
    r[2] = (short)f2bf(a.z); r[3] = (short)f2bf(a.w);
    r[4] = (short)f2bf(b.x); r[5] = (short)f2bf(b.y);
    r[6] = (short)f2bf(b.z); r[7] = (short)f2bf(b.w);
    return r;
}

// ---------------------------------------------------------------------------
// Stage proj (128x64 fp32, *DNORM) into MFMA fragment order in LDS.
// Slot layout per 16-row tile i, half h: slot s = dg*16+m holds rows m,
// cols h*32 + dg*8 .. +7 (verified round 3-8).
// ---------------------------------------------------------------------------
__device__ __forceinline__ void stage_proj(const float* __restrict__ proj,
                                           unsigned short (*F)[2][64][8], int t) {
    const float4* g = reinterpret_cast<const float4*>(proj);
#pragma unroll
    for (int i = 0; i < 8; ++i) {
        int c = t & 15;            // chunk within row (4 floats)
        int m = t >> 4;            // row within 16-row tile
        float4 v = g[t + i * 256];
        v.x *= DNORM; v.y *= DNORM; v.z *= DNORM; v.w *= DNORM;
        int h = c >> 3, dg = (c >> 1) & 3, half = c & 1;
        uint2 wv;
        wv.x = (unsigned int)f2bf(v.x) | ((unsigned int)f2bf(v.y) << 16);
        wv.y = (unsigned int)f2bf(v.z) | ((unsigned int)f2bf(v.w) << 16);
        *reinterpret_cast<uint2*>(&F[i][h][dg * 16 + m][half * 4]) = wv;
    }
}

// ---------------------------------------------------------------------------
// Direct-from-global data fragments + in-register diag.
// Wave w owns tiles w*2, w*2+1 (rows tr*16 + (l&15)). Lane l loads its own
// fragment: row (tr*16 + (l&15)), cols (l>>4)*8 (+32 for h=1), 8 floats each.
// Per instruction the wave touches 16 rows x 128B-contiguous -> L2 assembles
// full lines. diag: lanes {l, l^16, l^32, l^48} share a row -> 2 shuffles.
// ---------------------------------------------------------------------------
__device__ __forceinline__ void load_data_frags(const float* __restrict__ base,
                                                int l, int w,
                                                bf16x8 fd[2][2], float diag[2]) {
#pragma unroll
    for (int r = 0; r < 2; ++r) {
        const float* rp = base + ((w * 2 + r) * 16 + (l & 15)) * 64 + (l >> 4) * 8;
        float4 a0 = *reinterpret_cast<const float4*>(rp);
        float4 b0 = *reinterpret_cast<const float4*>(rp + 4);
        float4 a1 = *reinterpret_cast<const float4*>(rp + 32);
        float4 b1 = *reinterpret_cast<const float4*>(rp + 36);
        fd[r][0] = pack8(a0, b0);
        fd[r][1] = pack8(a1, b1);
        float ss = a0.x*a0.x + a0.y*a0.y + a0.z*a0.z + a0.w*a0.w
                 + b0.x*b0.x + b0.y*b0.y + b0.z*b0.z + b0.w*b0.w
                 + a1.x*a1.x + a1.y*a1.y + a1.z*a1.z + a1.w*a1.w
                 + b1.x*b1.x + b1.y*b1.y + b1.z*b1.z + b1.w*b1.w;
        ss += __shfl_xor(ss, 16, 64);
        ss += __shfl_xor(ss, 32, 64);
        diag[r] = ss * DIAG_F;
    }
}

// MFMA core: acc[r][pt] = proj-tile(pt) x data-tile(w*2+r).
// D-layout: data row = lane&15, feature sub-idx = (lane>>4)*4 + reg.
__device__ __forceinline__ void mfma_tiles(const bf16x8 fd[2][2],
                                           unsigned short (*Ps)[2][64][8],
                                           int l, f32x4 acc[2][8]) {
#pragma unroll
    for (int r = 0; r < 2; ++r)
#pragma unroll
        for (int pt = 0; pt < 8; ++pt)
            acc[r][pt] = f32x4{0.f, 0.f, 0.f, 0.f};
#pragma unroll
    for (int pt = 0; pt < 8; ++pt) {
        bf16x8 fp0 = *reinterpret_cast<bf16x8*>(&Ps[pt][0][l][0]);
        bf16x8 fp1 = *reinterpret_cast<bf16x8*>(&Ps[pt][1][l][0]);
#pragma unroll
        for (int r = 0; r < 2; ++r) {
            acc[r][pt] = __builtin_amdgcn_mfma_f32_16x16x32_bf16(fp0, fd[r][0], acc[r][pt], 0, 0, 0);
            acc[r][pt] = __builtin_amdgcn_mfma_f32_16x16x32_bf16(fp1, fd[r][1], acc[r][pt], 0, 0, 0);
        }
    }
}

// ---------------------------------------------------------------------------
// k max pass: per-block max of (|x| - diag) - HLM -> partials[bid]
// ---------------------------------------------------------------------------
__global__ __launch_bounds__(256, 4) void kmax_kernel(
        const float* __restrict__ k, const float* __restrict__ proj,
        float* __restrict__ partials) {
    __shared__ unsigned short Ps[8][2][64][8];
    __shared__ float red[4];
    int t = threadIdx.x;
    int l = t & 63, w = t >> 6;
    stage_proj(proj, Ps, t);
    bf16x8 fd[2][2];
    float diag[2];
    load_data_frags(k + (size_t)blockIdx.x * ROWS_PER_BLK * 64, l, w, fd, diag);
    __syncthreads();
    f32x4 acc[2][8];
    mfma_tiles(fd, Ps, l, acc);

    float cand = -INFINITY;
#pragma unroll
    for (int r = 0; r < 2; ++r) {
        float mx = 0.f;
#pragma unroll
        for (int pt = 0; pt < 8; ++pt) {
            f32x4 a = acc[r][pt];
            mx = fmaxf(mx, fmaxf(fmaxf(fabsf(a[0]), fabsf(a[1])),
                                 fmaxf(fabsf(a[2]), fabsf(a[3]))));
        }
        cand = fmaxf(cand, mx - diag[r]);
    }
#pragma unroll
    for (int s = 32; s; s >>= 1) cand = fmaxf(cand, __shfl_xor(cand, s, 64));
    if (l == 0) red[w] = cand;
    __syncthreads();
    if (t == 0)
        partials[blockIdx.x] =
            fmaxf(fmaxf(red[0], red[1]), fmaxf(red[2], red[3])) - HLM;
}

// ---------------------------------------------------------------------------
// Merged feature kernel: blocks [0,2048) = k (L3-hot from kmax), rest = q.
// Proj LDS and out-bounce LDS are unioned (disjoint lifetimes, barrier
// between). Epilogue: full-1KB-row streaming NT stores via per-wave LDS
// bounce with wave-local fences (round-8 verified).
// ---------------------------------------------------------------------------
__global__ __launch_bounds__(256, 4) void feat_kernel(
        const float* __restrict__ q, const float* __restrict__ k,
        const float* __restrict__ proj, const float* __restrict__ partials,
        float* __restrict__ qf, float* __restrict__ qls,
        float* __restrict__ kf, float* __restrict__ kls) {
    __shared__ __align__(16) unsigned char smem[4 * 8 * OB_STRIDE * 4];  // 33792 B
    __shared__ float gls_s;
    auto Ps = reinterpret_cast<unsigned short(*)[2][64][8]>(smem);
    float* outb = reinterpret_cast<float*>(smem);

    int t = threadIdx.x;
    int l = t & 63, w = t >> 6;
    bool is_q = blockIdx.x >= NBLOCKS;
    int bid = is_q ? (blockIdx.x - NBLOCKS) : blockIdx.x;
    const float* data = is_q ? q : k;
    float* feats = is_q ? qf : kf;

    stage_proj(proj, Ps, t);
    bf16x8 fd[2][2];
    float diag[2];
    load_data_frags(data + (size_t)bid * ROWS_PER_BLK * 64, l, w, fd, diag);
    if (!is_q && t < 32) {
        float v = partials[(bid >> 5) * BLKS_PER_BH + t];
#pragma unroll
        for (int s = 16; s; s >>= 1) v = fmaxf(v, __shfl_xor(v, s, 64));
        if (t == 0) gls_s = v;
    }
    __syncthreads();
    f32x4 acc[2][8];
    mfma_tiles(fd, Ps, l, acc);

    float gls = 0.f;
    if (!is_q) {
        gls = gls_s;
        if ((bid & 31) == 0 && t == 0) kls[bid >> 5] = gls;
    }
    __syncthreads();   // all waves done reading Ps before bounce reuse

    float* ob = outb + w * (8 * OB_STRIDE);
    int myrow = l & 15;         // row within this wave's 16-row tile
    int g = l >> 4;             // 4-feature sub-chunk index

#pragma unroll
    for (int r = 0; r < 2; ++r) {
        float off;
        if (is_q) {
            float mx = 0.f;     // max over concat[x,-x] = max |x|
#pragma unroll
            for (int pt = 0; pt < 8; ++pt) {
                f32x4 a = acc[r][pt];
                mx = fmaxf(mx, fmaxf(fmaxf(fabsf(a[0]), fabsf(a[1])),
                                     fmaxf(fabsf(a[2]), fabsf(a[3]))));
            }
            mx = fmaxf(mx, __shfl_xor(mx, 16, 64));
            mx = fmaxf(mx, __shfl_xor(mx, 32, 64));
            off = mx;
        } else {
            off = diag[r] + HLM + gls;
        }

#pragma unroll
        for (int p = 0; p < 2; ++p) {
            if ((myrow >> 3) == p) {
                float* obr = ob + (myrow & 7) * OB_STRIDE + g * 4;
#pragma unroll
                for (int pt = 0; pt < 8; ++pt) {
                    f32x4 a = acc[r][pt];
                    f32x4 e1, e2;
                    e1[0] = __expf(a[0] - off); e1[1] = __expf(a[1] - off);
                    e1[2] = __expf(a[2] - off); e1[3] = __expf(a[3] - off);
                    e2[0] = __expf(-a[0] - off); e2[1] = __expf(-a[1] - off);
                    e2[2] = __expf(-a[2] - off); e2[3] = __expf(-a[3] - off);
                    *reinterpret_cast<f32x4*>(obr + pt * 16)       = e1;
                    *reinterpret_cast<f32x4*>(obr + pt * 16 + 128) = e2;
                }
            }
            LDS_FENCE();   // fill (cross-lane) visible before drain reads
            size_t Rb = (size_t)bid * ROWS_PER_BLK + (w * 2 + r) * 16 + p * 8;
#pragma unroll
            for (int j = 0; j < 8; ++j) {
                f32x4 v = *reinterpret_cast<f32x4*>(ob + j * OB_STRIDE + l * 4);
                __builtin_nontemporal_store(
                    v, reinterpret_cast<f32x4*>(feats + (Rb + j) * 256 + l * 4));
            }
            LDS_FENCE();   // drain done before next fill overwrites (WAR)
        }
        if (is_q && l < 16) {
            size_t R = (size_t)bid * ROWS_PER_BLK + (w * 2 + r) * 16 + myrow;
            qls[R] = off - diag[r] - HLM;
        }
    }
}

extern "C" void kernel_launch(void* const* d_in, const int* in_sizes, int n_in,
                              void* d_out, int out_size, void* d_ws, size_t ws_size,
                              hipStream_t stream) {
    const float* q    = (const float*)d_in[0];
    const float* k    = (const float*)d_in[1];
    const float* proj = (const float*)d_in[2];

    float* out = (float*)d_out;
    float* qf  = out;                                       // (B,H,S,256)
    float* qls = out + (size_t)FEAT_ELEMS;                  // (B,H,S,1)
    float* kf  = out + (size_t)FEAT_ELEMS + ROWS_TOTAL;     // (B,H,S,256)
    float* kls = out + 2 * (size_t)FEAT_ELEMS + ROWS_TOTAL; // (B,H,1,1)

    float* partials = (float*)d_ws;                         // 2048 floats

    kmax_kernel<<<NBLOCKS, 256, 0, stream>>>(k, proj, partials);
    feat_kernel<<<2 * NBLOCKS, 256, 0, stream>>>(q, k, proj, partials,
                                                 qf, qls, kf, kls);
}